// Round 8
// baseline (455.675 us; speedup 1.0000x reference)
//
#include <hip/hip_runtime.h>

// RGCN layer, basis-decomposed, atomic-free LDS aggregation via dst-binning.
//
// Identity (validated rounds 2-5):
//   xc[n, b*8+j]  = sum_{t<16} x[n, 16j+t] * w_comp[t,b]
//   acc[n, k2], k2 = b*128 + et*8 + j, accumulates norm_e * xc[src_e, b*8+j]
//   out[n,o] = sum_{k2} acc[n,k2] * WbFlat[k2,o]
//
// LDS slot within a node row: s = et*32 + j*4 + b  (0..511)
// acc layout: node-major accf[ln*516 + s] (RS=516 keeps phase-B reads 2-way max,
// phase-A writes 32-bank conflict-free; both measured free).
//
// Workspace layout (51.4 MB):
//   [0,200000)            cnt[50000] i32
//   [200000,200064)       spillcnt i32 (+pad)
//   [200064,6600064)      spill[1.6M] i32
//   [6600064,45000064)    bins[50000][96] uint2 {src|(et<<17), norm bits}
//   [45000064,51400064)   xc[50000][32] f32

#define N_NODES  50000
#define N_EDGES  1600000
#define IN_FEAT  128
#define OUT_FEAT 128
#define NUM_RELS 16
#define NUM_BASES 4
#define XC_K     32
#define BIN_CAP  96
#define NPB      16          // nodes per block in fused kernel
#define RS       516         // acc row stride in floats (512 + 4 pad)
#define ACCF_WORDS 8704      // max(16*516=8256, reduction 256*34=8704)

#define OFF_CNT      0
#define OFF_SPILLCNT 200000
#define OFF_SPILL    200064
#define OFF_BINS     6600064
#define OFF_XC       45000064
#define WS_NEED      51400064

// ---------------- precomp_k: xc[n, b*8+j] = sum_t x[n,16j+t]*w_comp[t,b] -----
__global__ __launch_bounds__(256) void precomp_k(
    const float* __restrict__ x, const float* __restrict__ w_comp,
    float* __restrict__ xc)
{
  const int lane = threadIdx.x & 31;
  const int grp  = threadIdx.x >> 5;
  const int j = lane & 7;
  const int b = lane >> 3;
  float wc[16];
  #pragma unroll
  for (int t = 0; t < 16; ++t) wc[t] = w_comp[t * NUM_BASES + b];
  const int n = blockIdx.x * 8 + grp;          // grid 6250 covers exactly
  if (n < N_NODES) {
    const float4* xr = (const float4*)(x + (size_t)n * IN_FEAT) + j * 4;
    float acc = 0.f;
    #pragma unroll
    for (int q = 0; q < 4; ++q) {
      float4 v = xr[q];
      acc += v.x * wc[q*4+0] + v.y * wc[q*4+1]
           + v.z * wc[q*4+2] + v.w * wc[q*4+3];
    }
    xc[n * XC_K + lane] = acc;
  }
}

// ---------------- bin_k: scatter edges into per-dst bins ---------------------
__global__ __launch_bounds__(256) void bin_k(
    const int* __restrict__ src, const int* __restrict__ dst,
    const int* __restrict__ etype, const float* __restrict__ norm,
    int* __restrict__ cnt, uint2* __restrict__ bins,
    int* __restrict__ spillcnt, int* __restrict__ spill)
{
  const int e4 = (blockIdx.x * 256 + threadIdx.x) * 4;
  if (e4 < N_EDGES) {                      // N_EDGES % 4 == 0
    const int4   s4 = *(const int4*)&src[e4];
    const int4   d4 = *(const int4*)&dst[e4];
    const int4   t4 = *(const int4*)&etype[e4];
    const float4 n4 = *(const float4*)&norm[e4];
    const int   ss[4] = {s4.x, s4.y, s4.z, s4.w};
    const int   dd[4] = {d4.x, d4.y, d4.z, d4.w};
    const int   tt[4] = {t4.x, t4.y, t4.z, t4.w};
    const float nn[4] = {n4.x, n4.y, n4.z, n4.w};
    #pragma unroll
    for (int q = 0; q < 4; ++q) {
      const int pos = atomicAdd(&cnt[dd[q]], 1);
      if (pos < BIN_CAP) {
        bins[(size_t)dd[q] * BIN_CAP + pos] =
            make_uint2((unsigned)ss[q] | ((unsigned)tt[q] << 17),
                       __float_as_uint(nn[q]));
      } else {
        const int k = atomicAdd(spillcnt, 1);
        if (k < N_EDGES) spill[k] = e4 + q;
      }
    }
  }
}

// ---------------- reduction helpers (k-split combine through LDS) ------------
__device__ inline void red_write(float* accf, int slot, float4 (&ac)[4][2]) {
  const int base = slot * 34;
  #pragma unroll
  for (int nn = 0; nn < 4; ++nn) {
    *(float2*)&accf[base + nn*8 + 0] = make_float2(ac[nn][0].x, ac[nn][0].y);
    *(float2*)&accf[base + nn*8 + 2] = make_float2(ac[nn][0].z, ac[nn][0].w);
    *(float2*)&accf[base + nn*8 + 4] = make_float2(ac[nn][1].x, ac[nn][1].y);
    *(float2*)&accf[base + nn*8 + 6] = make_float2(ac[nn][1].z, ac[nn][1].w);
  }
}
__device__ inline void red_read(const float* accf, int slot, float4 (&ac)[4][2]) {
  const int base = slot * 34;
  #pragma unroll
  for (int nn = 0; nn < 4; ++nn) {
    float2 v0 = *(const float2*)&accf[base + nn*8 + 0];
    float2 v1 = *(const float2*)&accf[base + nn*8 + 2];
    float2 v2 = *(const float2*)&accf[base + nn*8 + 4];
    float2 v3 = *(const float2*)&accf[base + nn*8 + 6];
    ac[nn][0].x += v0.x; ac[nn][0].y += v0.y;
    ac[nn][0].z += v1.x; ac[nn][0].w += v1.y;
    ac[nn][1].x += v2.x; ac[nn][1].y += v2.y;
    ac[nn][1].z += v3.x; ac[nn][1].w += v3.y;
  }
}

__device__ inline float selb(const float4& v, int bb) {
  return bb == 0 ? v.x : bb == 1 ? v.y : bb == 2 ? v.z : v.w;
}

__device__ inline unsigned clampsrc(unsigned v) {
  unsigned s = v & 0x1FFFFu;
  return s < (unsigned)N_NODES ? s : 0u;     // masked edges read garbage: clamp
}

// ---------------- fused gather (non-atomic LDS RMW) + block GEMM -------------
// 512 threads = 8 waves, 16 nodes/block (grid 3125 exact).
// Phase A: half-wave (w,h) exclusively owns node ln=2w+h; edges in groups of 4
//   with meta prefetched 2 groups ahead (uniform uint4 loads) and xc gathers
//   issued 1 group ahead -> ~6-8 outstanding xc loads/wave (vs 2 in round 5).
// Phase B: wave = k-split; lane = ng(4 nodes) x og(8 cols); tree-reduce 8 splits.
__global__ __launch_bounds__(512, 8) void rgcn_fused(
    const int* __restrict__ cnt, const uint2* __restrict__ bins,
    const float* __restrict__ xc, const float* __restrict__ Wb,
    float* __restrict__ out)
{
  __shared__ float accf[ACCF_WORDS];   // 34 KB -> 4 blocks/CU

  const int t    = threadIdx.x;
  const int w    = t >> 6;
  const int lane = t & 63;
  const int h    = lane >> 5;
  const int l5   = lane & 31;
  const int perm = (l5 & 7) * 4 + (l5 >> 3);   // j*4 + b

  for (int i = t; i < ACCF_WORDS / 4; i += 512)
    ((float4*)accf)[i] = make_float4(0.f, 0.f, 0.f, 0.f);
  __syncthreads();

  const int nodeBase = blockIdx.x * NPB;
  const int ln = w * 2 + h;                    // local node 0..15
  const int n  = nodeBase + ln;
  int c = cnt[n]; c = c > BIN_CAP ? BIN_CAP : c;
  const int cmax    = max(c, __shfl_xor(c, 32));
  const int ngroups = (cmax + 3) >> 2;         // groups of 4 edges

  const uint4* bp4 = (const uint4*)(bins + (size_t)n * BIN_CAP); // 2 edges/uint4
  const int awb = ln * RS + perm;

  // ---- phase A: 4-edge groups, meta +2 groups ahead, xc +1 group ahead ----
  if (ngroups > 0) {
    uint4 m0a = bp4[0], m0b = bp4[1];          // group 0 meta
    uint4 m1a = bp4[2], m1b = bp4[3];          // group 1 meta
    float x0 = xc[(size_t)clampsrc(m0a.x) * XC_K + l5];
    float x1 = xc[(size_t)clampsrc(m0a.z) * XC_K + l5];
    float x2 = xc[(size_t)clampsrc(m0b.x) * XC_K + l5];
    float x3 = xc[(size_t)clampsrc(m0b.z) * XC_K + l5];

    #pragma unroll 2
    for (int g = 0; g < ngroups; ++g) {
      // prefetch meta for group g+2 (stays within d_ws; data masked if unused)
      const uint4 pa = bp4[2 * g + 4];
      const uint4 pb = bp4[2 * g + 5];
      // issue xc gathers for group g+1
      const float y0 = xc[(size_t)clampsrc(m1a.x) * XC_K + l5];
      const float y1 = xc[(size_t)clampsrc(m1a.z) * XC_K + l5];
      const float y2 = xc[(size_t)clampsrc(m1b.x) * XC_K + l5];
      const float y3 = xc[(size_t)clampsrc(m1b.z) * XC_K + l5];
      // consume group g (masked by count; non-atomic: half-wave owns row ln)
      const int e0 = 4 * g;
      const float v0 = (e0     < c) ? __uint_as_float(m0a.y) : 0.f;
      const float v1 = (e0 + 1 < c) ? __uint_as_float(m0a.w) : 0.f;
      const float v2 = (e0 + 2 < c) ? __uint_as_float(m0b.y) : 0.f;
      const float v3 = (e0 + 3 < c) ? __uint_as_float(m0b.w) : 0.f;
      accf[awb + (int)((m0a.x >> 17) & 15) * 32] += x0 * v0;
      accf[awb + (int)((m0a.z >> 17) & 15) * 32] += x1 * v1;
      accf[awb + (int)((m0b.x >> 17) & 15) * 32] += x2 * v2;
      accf[awb + (int)((m0b.z >> 17) & 15) * 32] += x3 * v3;
      // rotate ring (static names; unroll 2 elides most moves)
      m0a = m1a; m0b = m1b; m1a = pa; m1b = pb;
      x0 = y0; x1 = y1; x2 = y2; x3 = y3;
    }
  }
  __syncthreads();

  // ---- phase B: out[16,128] = acc[16,512] @ Wb[512,128], k-split by wave ----
  const int ks = w;
  const int ng = lane & 3;       // nodes ng*4 .. ng*4+3
  const int og = lane >> 2;      // cols og*8 .. og*8+7
  const float* wbase = Wb + og * 8;

  float4 ac[4][2];
  #pragma unroll
  for (int nn = 0; nn < 4; ++nn) {
    ac[nn][0] = make_float4(0.f, 0.f, 0.f, 0.f);
    ac[nn][1] = make_float4(0.f, 0.f, 0.f, 0.f);
  }

  #pragma unroll 4
  for (int q = 0; q < 16; ++q) {
    const int k0 = ks * 64 + q * 4;                  // slot base; b = 0..3 inside
    const int r0 = (k0 >> 5) * 8 + ((k0 >> 2) & 7);  // et*8 + j
    float4 a4[4];
    #pragma unroll
    for (int nn = 0; nn < 4; ++nn)
      a4[nn] = *(const float4*)&accf[(ng * 4 + nn) * RS + k0];
    #pragma unroll
    for (int bb = 0; bb < 4; ++bb) {
      const float* wr = wbase + (size_t)(bb * 128 + r0) * 128;
      const float4 w0 = *(const float4*)wr;
      const float4 w1 = *(const float4*)(wr + 4);
      #pragma unroll
      for (int nn = 0; nn < 4; ++nn) {
        const float s = selb(a4[nn], bb);
        ac[nn][0].x += s * w0.x; ac[nn][0].y += s * w0.y;
        ac[nn][0].z += s * w0.z; ac[nn][0].w += s * w0.w;
        ac[nn][1].x += s * w1.x; ac[nn][1].y += s * w1.y;
        ac[nn][1].z += s * w1.z; ac[nn][1].w += s * w1.w;
      }
    }
  }

  // ---- combine 8 k-splits: 4 -> 2 -> 1 ----
  __syncthreads();
  if (ks >= 4)             red_write(accf, (ks - 4) * 64 + lane, ac);
  __syncthreads();
  if (ks < 4)              red_read (accf, ks * 64 + lane, ac);
  __syncthreads();
  if (ks == 2 || ks == 3)  red_write(accf, (ks - 2) * 64 + lane, ac);
  __syncthreads();
  if (ks < 2)              red_read (accf, ks * 64 + lane, ac);
  __syncthreads();
  if (ks == 1)             red_write(accf, lane, ac);
  __syncthreads();
  if (ks == 0) {
    red_read(accf, lane, ac);
    #pragma unroll
    for (int nn = 0; nn < 4; ++nn) {
      const int node = nodeBase + ng * 4 + nn;
      *(float4*)(out + (size_t)node * OUT_FEAT + og * 8)     = ac[nn][0];
      *(float4*)(out + (size_t)node * OUT_FEAT + og * 8 + 4) = ac[nn][1];
    }
  }
}

// ---------------- spill fix (bin overflow; normally 0 edges) ----------------
__global__ __launch_bounds__(256) void spill_fix(
    const int* __restrict__ spillcnt, const int* __restrict__ spill,
    const float* __restrict__ xc, const float* __restrict__ Wb,
    const float* __restrict__ norm, const int* __restrict__ src,
    const int* __restrict__ dst, const int* __restrict__ etype,
    float* __restrict__ out)
{
  int cntv = *spillcnt; if (cntv > N_EDGES) cntv = N_EDGES;
  for (int idx = blockIdx.x * blockDim.x + threadIdx.x; idx < cntv;
       idx += gridDim.x * blockDim.x) {
    const int e = spill[idx];
    const int s = src[e], d = dst[e], et = etype[e];
    const float nm = norm[e];
    float m[32];
    #pragma unroll
    for (int l = 0; l < 32; ++l) m[l] = xc[(size_t)s * XC_K + l] * nm;
    for (int o = 0; o < OUT_FEAT; ++o) {
      float a = 0.f;
      #pragma unroll
      for (int l = 0; l < 32; ++l)
        a += m[l] * Wb[(size_t)((l >> 3) * 128 + et * 8 + (l & 7)) * OUT_FEAT + o];
      atomicAdd(&out[(size_t)d * OUT_FEAT + o], a);
    }
  }
}

// ---------------- fallback (tiny d_ws): direct edge -> out atomics -----------
__global__ __launch_bounds__(256) void edge_direct(
    const float* __restrict__ x, const float* __restrict__ W_bases,
    const float* __restrict__ w_comp, const float* __restrict__ norm,
    const int* __restrict__ src, const int* __restrict__ dst,
    const int* __restrict__ etype, float* __restrict__ out)
{
  const int wave = threadIdx.x >> 6;
  const int lane = threadIdx.x & 63;
  const int j = lane & 7;
  const int b = (lane >> 3) & 3;
  float wc[16];
  #pragma unroll
  for (int t = 0; t < 16; ++t) wc[t] = w_comp[t * NUM_BASES + b];
  for (int e = blockIdx.x * 4 + wave; e < N_EDGES; e += gridDim.x * 4) {
    const int s = src[e], d = dst[e], et = etype[e];
    const float nm = norm[e];
    const float4* xr = (const float4*)(x + (size_t)s * IN_FEAT) + j * 4;
    float m = 0.f;
    #pragma unroll
    for (int q = 0; q < 4; ++q) {
      float4 v = xr[q];
      m += v.x * wc[q*4+0] + v.y * wc[q*4+1]
         + v.z * wc[q*4+2] + v.w * wc[q*4+3];
    }
    m *= nm;
    float acc0 = 0.f, acc1 = 0.f;
    #pragma unroll
    for (int p = 0; p < 32; ++p) {
      float mv = __shfl(m, p, 64);
      const float* Wr = W_bases + (size_t)((p >> 3) * 128 + et * 8 + (p & 7)) * OUT_FEAT;
      acc0 += mv * Wr[lane];
      acc1 += mv * Wr[64 + lane];
    }
    atomicAdd(out + (size_t)d * OUT_FEAT + lane, acc0);
    atomicAdd(out + (size_t)d * OUT_FEAT + 64 + lane, acc1);
  }
}

extern "C" void kernel_launch(void* const* d_in, const int* in_sizes, int n_in,
                              void* d_out, int out_size, void* d_ws, size_t ws_size,
                              hipStream_t stream) {
  const float* x       = (const float*)d_in[0];
  const float* W_bases = (const float*)d_in[1];   // flat [512][128]
  const float* w_comp  = (const float*)d_in[2];
  const float* norm    = (const float*)d_in[3];
  const int*   src     = (const int*)d_in[4];
  const int*   dst     = (const int*)d_in[5];
  const int*   etype   = (const int*)d_in[6];
  float* out = (float*)d_out;

  if (ws_size >= (size_t)WS_NEED) {
    char* ws = (char*)d_ws;
    int*   cntp     = (int*)(ws + OFF_CNT);
    int*   spillcnt = (int*)(ws + OFF_SPILLCNT);
    int*   spill    = (int*)(ws + OFF_SPILL);
    uint2* bins     = (uint2*)(ws + OFF_BINS);
    float* xc       = (float*)(ws + OFF_XC);

    hipMemsetAsync(cntp, 0, 200064, stream);   // cnt + spillcnt
    precomp_k<<<6250, 256, 0, stream>>>(x, w_comp, xc);
    bin_k<<<1563, 256, 0, stream>>>(src, dst, etype, norm,
                                    cntp, bins, spillcnt, spill);
    rgcn_fused<<<N_NODES / NPB, 512, 0, stream>>>(cntp, bins, xc, W_bases, out);
    spill_fix<<<16, 256, 0, stream>>>(spillcnt, spill, xc, W_bases,
                                      norm, src, dst, etype, out);
  } else {
    hipMemsetAsync(out, 0, (size_t)out_size * sizeof(float), stream);
    edge_direct<<<8192, 256, 0, stream>>>(x, W_bases, w_comp, norm,
                                          src, dst, etype, out);
  }
}

// Round 9
// 380.788 us; speedup vs baseline: 1.1967x; 1.1967x over previous
//
#include <hip/hip_runtime.h>

// RGCN layer, basis-decomposed, atomic-free LDS aggregation via dst-binning.
//
// Identity (validated rounds 2-8):
//   xc[n, b*8+j]  = sum_{t<16} x[n, 16j+t] * w_comp[t,b]
//   acc[n, k2], k2 = b*128 + et*8 + j, accumulates norm_e * xc[src_e, b*8+j]
//   out[n,o] = sum_{k2} acc[n,k2] * WbFlat[k2,o]
//
// ROUND 9 CHANGE (only): __launch_bounds__(512, 8) -> (512, 4).
// Round 8 counters showed WRITE_SIZE = 124 MB vs 25.6 MB of real output and
// VGPR_Count = 32: the min-occupancy pin forced ~15 dwords/thread of scratch
// spills (ring + ac[4][2] accumulators). 128-VGPR cap removes memory spills;
// 16 waves/CU is still enough (phase A needs ~24 loads in flight/SIMD,
// phase B is VALU-issue-bound at 4 waves/SIMD).
//
// Workspace layout (51.4 MB):
//   [0,200000)            cnt[50000] i32
//   [200000,200064)       spillcnt i32 (+pad)
//   [200064,6600064)      spill[1.6M] i32
//   [6600064,45000064)    bins[50000][96] uint2 {src|(et<<17), norm bits}
//   [45000064,51400064)   xc[50000][32] f32

#define N_NODES  50000
#define N_EDGES  1600000
#define IN_FEAT  128
#define OUT_FEAT 128
#define NUM_RELS 16
#define NUM_BASES 4
#define XC_K     32
#define BIN_CAP  96
#define NPB      16          // nodes per block in fused kernel
#define RS       516         // acc row stride in floats (512 + 4 pad)
#define ACCF_WORDS 8704      // max(16*516=8256, reduction 256*34=8704)

#define OFF_CNT      0
#define OFF_SPILLCNT 200000
#define OFF_SPILL    200064
#define OFF_BINS     6600064
#define OFF_XC       45000064
#define WS_NEED      51400064

// ---------------- precomp_k: xc[n, b*8+j] = sum_t x[n,16j+t]*w_comp[t,b] -----
__global__ __launch_bounds__(256) void precomp_k(
    const float* __restrict__ x, const float* __restrict__ w_comp,
    float* __restrict__ xc)
{
  const int lane = threadIdx.x & 31;
  const int grp  = threadIdx.x >> 5;
  const int j = lane & 7;
  const int b = lane >> 3;
  float wc[16];
  #pragma unroll
  for (int t = 0; t < 16; ++t) wc[t] = w_comp[t * NUM_BASES + b];
  const int n = blockIdx.x * 8 + grp;          // grid 6250 covers exactly
  if (n < N_NODES) {
    const float4* xr = (const float4*)(x + (size_t)n * IN_FEAT) + j * 4;
    float acc = 0.f;
    #pragma unroll
    for (int q = 0; q < 4; ++q) {
      float4 v = xr[q];
      acc += v.x * wc[q*4+0] + v.y * wc[q*4+1]
           + v.z * wc[q*4+2] + v.w * wc[q*4+3];
    }
    xc[n * XC_K + lane] = acc;
  }
}

// ---------------- bin_k: scatter edges into per-dst bins ---------------------
__global__ __launch_bounds__(256) void bin_k(
    const int* __restrict__ src, const int* __restrict__ dst,
    const int* __restrict__ etype, const float* __restrict__ norm,
    int* __restrict__ cnt, uint2* __restrict__ bins,
    int* __restrict__ spillcnt, int* __restrict__ spill)
{
  const int e4 = (blockIdx.x * 256 + threadIdx.x) * 4;
  if (e4 < N_EDGES) {                      // N_EDGES % 4 == 0
    const int4   s4 = *(const int4*)&src[e4];
    const int4   d4 = *(const int4*)&dst[e4];
    const int4   t4 = *(const int4*)&etype[e4];
    const float4 n4 = *(const float4*)&norm[e4];
    const int   ss[4] = {s4.x, s4.y, s4.z, s4.w};
    const int   dd[4] = {d4.x, d4.y, d4.z, d4.w};
    const int   tt[4] = {t4.x, t4.y, t4.z, t4.w};
    const float nn[4] = {n4.x, n4.y, n4.z, n4.w};
    #pragma unroll
    for (int q = 0; q < 4; ++q) {
      const int pos = atomicAdd(&cnt[dd[q]], 1);
      if (pos < BIN_CAP) {
        bins[(size_t)dd[q] * BIN_CAP + pos] =
            make_uint2((unsigned)ss[q] | ((unsigned)tt[q] << 17),
                       __float_as_uint(nn[q]));
      } else {
        const int k = atomicAdd(spillcnt, 1);
        if (k < N_EDGES) spill[k] = e4 + q;
      }
    }
  }
}

// ---------------- reduction helpers (k-split combine through LDS) ------------
__device__ inline void red_write(float* accf, int slot, float4 (&ac)[4][2]) {
  const int base = slot * 34;
  #pragma unroll
  for (int nn = 0; nn < 4; ++nn) {
    *(float2*)&accf[base + nn*8 + 0] = make_float2(ac[nn][0].x, ac[nn][0].y);
    *(float2*)&accf[base + nn*8 + 2] = make_float2(ac[nn][0].z, ac[nn][0].w);
    *(float2*)&accf[base + nn*8 + 4] = make_float2(ac[nn][1].x, ac[nn][1].y);
    *(float2*)&accf[base + nn*8 + 6] = make_float2(ac[nn][1].z, ac[nn][1].w);
  }
}
__device__ inline void red_read(const float* accf, int slot, float4 (&ac)[4][2]) {
  const int base = slot * 34;
  #pragma unroll
  for (int nn = 0; nn < 4; ++nn) {
    float2 v0 = *(const float2*)&accf[base + nn*8 + 0];
    float2 v1 = *(const float2*)&accf[base + nn*8 + 2];
    float2 v2 = *(const float2*)&accf[base + nn*8 + 4];
    float2 v3 = *(const float2*)&accf[base + nn*8 + 6];
    ac[nn][0].x += v0.x; ac[nn][0].y += v0.y;
    ac[nn][0].z += v1.x; ac[nn][0].w += v1.y;
    ac[nn][1].x += v2.x; ac[nn][1].y += v2.y;
    ac[nn][1].z += v3.x; ac[nn][1].w += v3.y;
  }
}

__device__ inline float selb(const float4& v, int bb) {
  return bb == 0 ? v.x : bb == 1 ? v.y : bb == 2 ? v.z : v.w;
}

__device__ inline unsigned clampsrc(unsigned v) {
  unsigned s = v & 0x1FFFFu;
  return s < (unsigned)N_NODES ? s : 0u;     // masked edges read garbage: clamp
}

// ---------------- fused gather (non-atomic LDS RMW) + block GEMM -------------
// 512 threads = 8 waves, 16 nodes/block (grid 3125 exact).
// Phase A: half-wave (w,h) exclusively owns node ln=2w+h; edges in groups of 4
//   with meta prefetched 2 groups ahead (uniform uint4 loads) and xc gathers
//   issued 1 group ahead.
// Phase B: wave = k-split; lane = ng(4 nodes) x og(8 cols); tree-reduce 8 splits.
__global__ __launch_bounds__(512, 4) void rgcn_fused(
    const int* __restrict__ cnt, const uint2* __restrict__ bins,
    const float* __restrict__ xc, const float* __restrict__ Wb,
    float* __restrict__ out)
{
  __shared__ float accf[ACCF_WORDS];   // 34 KB

  const int t    = threadIdx.x;
  const int w    = t >> 6;
  const int lane = t & 63;
  const int h    = lane >> 5;
  const int l5   = lane & 31;
  const int perm = (l5 & 7) * 4 + (l5 >> 3);   // j*4 + b

  for (int i = t; i < ACCF_WORDS / 4; i += 512)
    ((float4*)accf)[i] = make_float4(0.f, 0.f, 0.f, 0.f);
  __syncthreads();

  const int nodeBase = blockIdx.x * NPB;
  const int ln = w * 2 + h;                    // local node 0..15
  const int n  = nodeBase + ln;
  int c = cnt[n]; c = c > BIN_CAP ? BIN_CAP : c;
  const int cmax    = max(c, __shfl_xor(c, 32));
  const int ngroups = (cmax + 3) >> 2;         // groups of 4 edges

  const uint4* bp4 = (const uint4*)(bins + (size_t)n * BIN_CAP); // 2 edges/uint4
  const int awb = ln * RS + perm;

  // ---- phase A: 4-edge groups, meta +2 groups ahead, xc +1 group ahead ----
  if (ngroups > 0) {
    uint4 m0a = bp4[0], m0b = bp4[1];          // group 0 meta
    uint4 m1a = bp4[2], m1b = bp4[3];          // group 1 meta
    float x0 = xc[(size_t)clampsrc(m0a.x) * XC_K + l5];
    float x1 = xc[(size_t)clampsrc(m0a.z) * XC_K + l5];
    float x2 = xc[(size_t)clampsrc(m0b.x) * XC_K + l5];
    float x3 = xc[(size_t)clampsrc(m0b.z) * XC_K + l5];

    #pragma unroll 2
    for (int g = 0; g < ngroups; ++g) {
      // prefetch meta for group g+2 (stays within d_ws; data masked if unused)
      const uint4 pa = bp4[2 * g + 4];
      const uint4 pb = bp4[2 * g + 5];
      // issue xc gathers for group g+1
      const float y0 = xc[(size_t)clampsrc(m1a.x) * XC_K + l5];
      const float y1 = xc[(size_t)clampsrc(m1a.z) * XC_K + l5];
      const float y2 = xc[(size_t)clampsrc(m1b.x) * XC_K + l5];
      const float y3 = xc[(size_t)clampsrc(m1b.z) * XC_K + l5];
      // consume group g (masked by count; non-atomic: half-wave owns row ln)
      const int e0 = 4 * g;
      const float v0 = (e0     < c) ? __uint_as_float(m0a.y) : 0.f;
      const float v1 = (e0 + 1 < c) ? __uint_as_float(m0a.w) : 0.f;
      const float v2 = (e0 + 2 < c) ? __uint_as_float(m0b.y) : 0.f;
      const float v3 = (e0 + 3 < c) ? __uint_as_float(m0b.w) : 0.f;
      accf[awb + (int)((m0a.x >> 17) & 15) * 32] += x0 * v0;
      accf[awb + (int)((m0a.z >> 17) & 15) * 32] += x1 * v1;
      accf[awb + (int)((m0b.x >> 17) & 15) * 32] += x2 * v2;
      accf[awb + (int)((m0b.z >> 17) & 15) * 32] += x3 * v3;
      // rotate ring (static names; unroll 2 elides most moves)
      m0a = m1a; m0b = m1b; m1a = pa; m1b = pb;
      x0 = y0; x1 = y1; x2 = y2; x3 = y3;
    }
  }
  __syncthreads();

  // ---- phase B: out[16,128] = acc[16,512] @ Wb[512,128], k-split by wave ----
  const int ks = w;
  const int ng = lane & 3;       // nodes ng*4 .. ng*4+3
  const int og = lane >> 2;      // cols og*8 .. og*8+7
  const float* wbase = Wb + og * 8;

  float4 ac[4][2];
  #pragma unroll
  for (int nn = 0; nn < 4; ++nn) {
    ac[nn][0] = make_float4(0.f, 0.f, 0.f, 0.f);
    ac[nn][1] = make_float4(0.f, 0.f, 0.f, 0.f);
  }

  #pragma unroll 4
  for (int q = 0; q < 16; ++q) {
    const int k0 = ks * 64 + q * 4;                  // slot base; b = 0..3 inside
    const int r0 = (k0 >> 5) * 8 + ((k0 >> 2) & 7);  // et*8 + j
    float4 a4[4];
    #pragma unroll
    for (int nn = 0; nn < 4; ++nn)
      a4[nn] = *(const float4*)&accf[(ng * 4 + nn) * RS + k0];
    #pragma unroll
    for (int bb = 0; bb < 4; ++bb) {
      const float* wr = wbase + (size_t)(bb * 128 + r0) * 128;
      const float4 w0 = *(const float4*)wr;
      const float4 w1 = *(const float4*)(wr + 4);
      #pragma unroll
      for (int nn = 0; nn < 4; ++nn) {
        const float s = selb(a4[nn], bb);
        ac[nn][0].x += s * w0.x; ac[nn][0].y += s * w0.y;
        ac[nn][0].z += s * w0.z; ac[nn][0].w += s * w0.w;
        ac[nn][1].x += s * w1.x; ac[nn][1].y += s * w1.y;
        ac[nn][1].z += s * w1.z; ac[nn][1].w += s * w1.w;
      }
    }
  }

  // ---- combine 8 k-splits: 4 -> 2 -> 1 ----
  __syncthreads();
  if (ks >= 4)             red_write(accf, (ks - 4) * 64 + lane, ac);
  __syncthreads();
  if (ks < 4)              red_read (accf, ks * 64 + lane, ac);
  __syncthreads();
  if (ks == 2 || ks == 3)  red_write(accf, (ks - 2) * 64 + lane, ac);
  __syncthreads();
  if (ks < 2)              red_read (accf, ks * 64 + lane, ac);
  __syncthreads();
  if (ks == 1)             red_write(accf, lane, ac);
  __syncthreads();
  if (ks == 0) {
    red_read(accf, lane, ac);
    #pragma unroll
    for (int nn = 0; nn < 4; ++nn) {
      const int node = nodeBase + ng * 4 + nn;
      *(float4*)(out + (size_t)node * OUT_FEAT + og * 8)     = ac[nn][0];
      *(float4*)(out + (size_t)node * OUT_FEAT + og * 8 + 4) = ac[nn][1];
    }
  }
}

// ---------------- spill fix (bin overflow; normally 0 edges) ----------------
__global__ __launch_bounds__(256) void spill_fix(
    const int* __restrict__ spillcnt, const int* __restrict__ spill,
    const float* __restrict__ xc, const float* __restrict__ Wb,
    const float* __restrict__ norm, const int* __restrict__ src,
    const int* __restrict__ dst, const int* __restrict__ etype,
    float* __restrict__ out)
{
  int cntv = *spillcnt; if (cntv > N_EDGES) cntv = N_EDGES;
  for (int idx = blockIdx.x * blockDim.x + threadIdx.x; idx < cntv;
       idx += gridDim.x * blockDim.x) {
    const int e = spill[idx];
    const int s = src[e], d = dst[e], et = etype[e];
    const float nm = norm[e];
    float m[32];
    #pragma unroll
    for (int l = 0; l < 32; ++l) m[l] = xc[(size_t)s * XC_K + l] * nm;
    for (int o = 0; o < OUT_FEAT; ++o) {
      float a = 0.f;
      #pragma unroll
      for (int l = 0; l < 32; ++l)
        a += m[l] * Wb[(size_t)((l >> 3) * 128 + et * 8 + (l & 7)) * OUT_FEAT + o];
      atomicAdd(&out[(size_t)d * OUT_FEAT + o], a);
    }
  }
}

// ---------------- fallback (tiny d_ws): direct edge -> out atomics -----------
__global__ __launch_bounds__(256) void edge_direct(
    const float* __restrict__ x, const float* __restrict__ W_bases,
    const float* __restrict__ w_comp, const float* __restrict__ norm,
    const int* __restrict__ src, const int* __restrict__ dst,
    const int* __restrict__ etype, float* __restrict__ out)
{
  const int wave = threadIdx.x >> 6;
  const int lane = threadIdx.x & 63;
  const int j = lane & 7;
  const int b = (lane >> 3) & 3;
  float wc[16];
  #pragma unroll
  for (int t = 0; t < 16; ++t) wc[t] = w_comp[t * NUM_BASES + b];
  for (int e = blockIdx.x * 4 + wave; e < N_EDGES; e += gridDim.x * 4) {
    const int s = src[e], d = dst[e], et = etype[e];
    const float nm = norm[e];
    const float4* xr = (const float4*)(x + (size_t)s * IN_FEAT) + j * 4;
    float m = 0.f;
    #pragma unroll
    for (int q = 0; q < 4; ++q) {
      float4 v = xr[q];
      m += v.x * wc[q*4+0] + v.y * wc[q*4+1]
         + v.z * wc[q*4+2] + v.w * wc[q*4+3];
    }
    m *= nm;
    float acc0 = 0.f, acc1 = 0.f;
    #pragma unroll
    for (int p = 0; p < 32; ++p) {
      float mv = __shfl(m, p, 64);
      const float* Wr = W_bases + (size_t)((p >> 3) * 128 + et * 8 + (p & 7)) * OUT_FEAT;
      acc0 += mv * Wr[lane];
      acc1 += mv * Wr[64 + lane];
    }
    atomicAdd(out + (size_t)d * OUT_FEAT + lane, acc0);
    atomicAdd(out + (size_t)d * OUT_FEAT + 64 + lane, acc1);
  }
}

extern "C" void kernel_launch(void* const* d_in, const int* in_sizes, int n_in,
                              void* d_out, int out_size, void* d_ws, size_t ws_size,
                              hipStream_t stream) {
  const float* x       = (const float*)d_in[0];
  const float* W_bases = (const float*)d_in[1];   // flat [512][128]
  const float* w_comp  = (const float*)d_in[2];
  const float* norm    = (const float*)d_in[3];
  const int*   src     = (const int*)d_in[4];
  const int*   dst     = (const int*)d_in[5];
  const int*   etype   = (const int*)d_in[6];
  float* out = (float*)d_out;

  if (ws_size >= (size_t)WS_NEED) {
    char* ws = (char*)d_ws;
    int*   cntp     = (int*)(ws + OFF_CNT);
    int*   spillcnt = (int*)(ws + OFF_SPILLCNT);
    int*   spill    = (int*)(ws + OFF_SPILL);
    uint2* bins     = (uint2*)(ws + OFF_BINS);
    float* xc       = (float*)(ws + OFF_XC);

    hipMemsetAsync(cntp, 0, 200064, stream);   // cnt + spillcnt
    precomp_k<<<6250, 256, 0, stream>>>(x, w_comp, xc);
    bin_k<<<1563, 256, 0, stream>>>(src, dst, etype, norm,
                                    cntp, bins, spillcnt, spill);
    rgcn_fused<<<N_NODES / NPB, 512, 0, stream>>>(cntp, bins, xc, W_bases, out);
    spill_fix<<<16, 256, 0, stream>>>(spillcnt, spill, xc, W_bases,
                                      norm, src, dst, etype, out);
  } else {
    hipMemsetAsync(out, 0, (size_t)out_size * sizeof(float), stream);
    edge_direct<<<8192, 256, 0, stream>>>(x, W_bases, w_comp, norm,
                                          src, dst, etype, out);
  }
}